// Round 9
// baseline (266.653 us; speedup 1.0000x reference)
//
#include <hip/hip_runtime.h>
#include <hip/hip_bf16.h>
#include <stdint.h>

#define NROWS 2048
#define DIM   4096
#define NACT  684
#define INV_TEMP 10.0f
#define NTILE128 136     // 16*17/2 upper-triangle 128x128 tiles
#define KIT   64         // DIM / 64 (MX K-step = 64), full K per tile
#define FP8_SCALE 16.0f  // Y stored as fp8(y*16); dot = 256*cos
#define OUT_SCALE (INV_TEMP / 256.0f)

// s_waitcnt immediates (gfx9/CDNA: vmcnt[3:0]@0, expcnt@4, lgkmcnt@8, vmcnt[5:4]@14)
#define WAITCNT_VM0   0x0F70
#define WAITCNT_VM4   0x0F74
#define WAITCNT_VM8   0x0F78

typedef __attribute__((ext_vector_type(4))) float floatx4;
typedef __attribute__((ext_vector_type(16))) float floatx16;
typedef __attribute__((ext_vector_type(4))) int intx4;
typedef __attribute__((ext_vector_type(8))) int intx8;
typedef __attribute__((ext_vector_type(8))) short shortx8;
typedef __attribute__((ext_vector_type(8))) unsigned short ushortx8;

static __device__ __forceinline__ unsigned short f32_to_bf16(float f) {
  union { float f; unsigned int u; } v; v.f = f;
  unsigned int u = v.u;
  unsigned int r = u + 0x7fffu + ((u >> 16) & 1u);
  return (unsigned short)(r >> 16);
}
static __device__ __forceinline__ float bf16_to_f32(unsigned short u) {
  union { unsigned int u; float f; } v; v.u = ((unsigned int)u) << 16;
  return v.f;
}
static __device__ __forceinline__ float f16_to_f32(unsigned short u) {
  union { unsigned short u; _Float16 h; } v; v.u = u;
  return (float)v.h;
}

// Pair tables: pa/pb per q; col-row delta = 4*(pb-pa) in {4,12}.
static __device__ __forceinline__ void num_store(float* __restrict__ NUM, int R, int delta,
                                                 float v) {
  if (delta == 4) {
    const int qs[4]  = {0, 1, 3, 4};
    const int pas[4] = {0, 1, 3, 4};
#pragma unroll
    for (int u = 0; u < 4; u++) {
      const int aa = (R - 4 * pas[u]) & (NROWS - 1);
      if (aa % 12 < 4) NUM[((aa / 12) * 4 + (aa % 12)) * 7 + qs[u]] = v;
    }
  } else {
    const int qs[3]  = {2, 5, 6};
    const int pas[3] = {0, 1, 2};
#pragma unroll
    for (int u = 0; u < 3; u++) {
      const int aa = (R - 4 * pas[u]) & (NROWS - 1);
      if (aa % 12 < 4) NUM[((aa / 12) * 4 + (aa % 12)) * 7 + qs[u]] = v;
    }
  }
}

// ------- Kernel 1A: per-row L2 norm + fp8 e4m3 convert (y*16); zeroes T/WS/out -------
__global__ __launch_bounds__(256) void k_normconv_fp8(const float* __restrict__ X,
                                                      unsigned char* __restrict__ Yq,
                                                      float* __restrict__ T,
                                                      float* __restrict__ WS,
                                                      float* __restrict__ out) {
  const int row = blockIdx.x;
  if (threadIdx.x == 0) T[row] = 0.f;
  if (row == 0 && threadIdx.x == 64) *out = 0.f;
  if (row < NACT && threadIdx.x >= 192 && threadIdx.x < 198)
    WS[row * 6 + (threadIdx.x - 192)] = 0.f;
  const float4* xr = (const float4*)(X + (size_t)row * DIM);
  float4 v[4];
  float s = 0.f;
#pragma unroll
  for (int t = 0; t < 4; t++) {
    float4 w = xr[threadIdx.x + t * 256];
    v[t] = w;
    s += w.x * w.x + w.y * w.y + w.z * w.z + w.w * w.w;
  }
#pragma unroll
  for (int off = 32; off > 0; off >>= 1) s += __shfl_down(s, off, 64);
  __shared__ float wsum[4];
  if ((threadIdx.x & 63) == 0) wsum[threadIdx.x >> 6] = s;
  __syncthreads();
  const float total = wsum[0] + wsum[1] + wsum[2] + wsum[3];
  const float sc = FP8_SCALE / fmaxf(sqrtf(total), 1e-30f);
  unsigned int* yr = (unsigned int*)(Yq + (size_t)row * DIM);
#pragma unroll
  for (int t = 0; t < 4; t++) {
    float4 w = v[t];
    unsigned int r0 = __builtin_amdgcn_cvt_pk_fp8_f32(w.x * sc, w.y * sc, 0, false);
    r0 = __builtin_amdgcn_cvt_pk_fp8_f32(w.z * sc, w.w * sc, r0, true);
    yr[threadIdx.x + t * 256] = r0;
  }
}

// ------- Kernel 2A: 128x128-tile FULL-K MX-fp8 GEMM + fused T/WS/NUM epilogue -------
// R8 post-mortem: the GEMM itself (R3/R8-proven pipeline, 142 MB staged) is fast, but
// the standalone combine kernel cost 48 us of pure exposed latency (all pipes <3%).
// R6 proved the same epilogue is ~free when FUSED (overlaps other blocks' memory waits).
// So: R8's 256-thread / VGPR~116 / 3-stage-ring / counted-vmcnt loop at KIT=64 (full K,
// no partials), then the R6/R7-verified epilogue from registers. 136 blocks; LDS 67 KB
// (ring 48 KB reused as tileE) -> 2 blocks/CU, all resident; no cross-block sync.
__global__ __launch_bounds__(256) void k_gemm_full(const unsigned char* __restrict__ Yq,
                                                   float* __restrict__ T,
                                                   float* __restrict__ WS,
                                                   float* __restrict__ NUM) {
  __shared__ __attribute__((aligned(16))) unsigned char lds[67072];
  // bijective XCD swizzle (136 = 8*17): consecutive logical tiles share an XCD.
  const int bid0 = blockIdx.x;
  const int t = (bid0 & 7) * 17 + (bid0 >> 3);
  int ti = 0, rem = t;
  while (rem >= 16 - ti) { rem -= 16 - ti; ti++; }
  const int tj = ti + rem;
  const int gr = ti * 128;
  const int gc = tj * 128;

  const int tid  = threadIdx.x;
  const int lane = tid & 63;
  const int wave = tid >> 6;
  const int wr = wave >> 1;
  const int wc = wave & 1;

  floatx16 zero = {0.f, 0.f, 0.f, 0.f, 0.f, 0.f, 0.f, 0.f,
                   0.f, 0.f, 0.f, 0.f, 0.f, 0.f, 0.f, 0.f};
  floatx16 acc[2][2];
#pragma unroll
  for (int i = 0; i < 2; i++)
#pragma unroll
    for (int j = 0; j < 2; j++) acc[i][j] = zero;

  // staging: thread t covers LDS bytes [16t,16t+16): row r2=t>>2, chunk t&3.
  // Source column pre-swizzled (linear dest + inverse-swizzled source + swizzled read).
  const int r2  = tid >> 2;
  const int c16 = tid & 3;
  const unsigned int swst = (unsigned)(((r2 >> 1) & 3) << 4);
  const unsigned int colst = ((unsigned)(c16 << 4)) ^ swst;
  const unsigned char* gA = Yq + (size_t)(gr + r2) * DIM + colst;
  const unsigned char* gB = Yq + (size_t)(gc + r2) * DIM + colst;

#define ISSUE(st, koff)                                                                  \
  do {                                                                                   \
    __builtin_amdgcn_global_load_lds(                                                    \
        (const __attribute__((address_space(1))) void*)(gA + (koff)),                    \
        (__attribute__((address_space(3))) void*)(lds + (st) * 16384 + tid * 16),        \
        16, 0, 0);                                                                       \
    __builtin_amdgcn_global_load_lds(                                                    \
        (const __attribute__((address_space(1))) void*)(gA + (size_t)64 * DIM + (koff)), \
        (__attribute__((address_space(3))) void*)(lds + (st) * 16384 + 4096 + tid * 16), \
        16, 0, 0);                                                                       \
    __builtin_amdgcn_global_load_lds(                                                    \
        (const __attribute__((address_space(1))) void*)(gB + (koff)),                    \
        (__attribute__((address_space(3))) void*)(lds + (st) * 16384 + 8192 + tid * 16), \
        16, 0, 0);                                                                       \
    __builtin_amdgcn_global_load_lds(                                                    \
        (const __attribute__((address_space(1))) void*)(gB + (size_t)64 * DIM + (koff)), \
        (__attribute__((address_space(3))) void*)(lds + (st) * 16384 + 12288 + tid * 16),\
        16, 0, 0);                                                                       \
  } while (0)

#define COMPUTE(st)                                                                      \
  do {                                                                                   \
    const unsigned char* bA = lds + (st) * 16384;                                        \
    const unsigned char* bB = bA + 8192;                                                 \
    const unsigned int c0 = (unsigned)((lane >> 5) << 5);                                \
    intx8 af[2], bf[2];                                                                  \
    _Pragma("unroll")                                                                    \
    for (int mi = 0; mi < 2; mi++) {                                                     \
      const int r = wr * 64 + mi * 32 + (lane & 31);                                     \
      const unsigned int sw = (unsigned)(((r >> 1) & 3) << 4);                           \
      const unsigned char* base = bA + r * 64;                                           \
      intx4 lo = *(const intx4*)(base + (c0 ^ sw));                                      \
      intx4 hi = *(const intx4*)(base + ((c0 ^ sw) ^ 16u));                              \
      intx8 v;                                                                           \
      v[0] = lo[0]; v[1] = lo[1]; v[2] = lo[2]; v[3] = lo[3];                            \
      v[4] = hi[0]; v[5] = hi[1]; v[6] = hi[2]; v[7] = hi[3];                            \
      af[mi] = v;                                                                        \
    }                                                                                    \
    _Pragma("unroll")                                                                    \
    for (int ni = 0; ni < 2; ni++) {                                                     \
      const int r = wc * 64 + ni * 32 + (lane & 31);                                     \
      const unsigned int sw = (unsigned)(((r >> 1) & 3) << 4);                           \
      const unsigned char* base = bB + r * 64;                                           \
      intx4 lo = *(const intx4*)(base + (c0 ^ sw));                                      \
      intx4 hi = *(const intx4*)(base + ((c0 ^ sw) ^ 16u));                              \
      intx8 v;                                                                           \
      v[0] = lo[0]; v[1] = lo[1]; v[2] = lo[2]; v[3] = lo[3];                            \
      v[4] = hi[0]; v[5] = hi[1]; v[6] = hi[2]; v[7] = hi[3];                            \
      bf[ni] = v;                                                                        \
    }                                                                                    \
    _Pragma("unroll")                                                                    \
    for (int mi = 0; mi < 2; mi++)                                                       \
      _Pragma("unroll")                                                                  \
      for (int ni = 0; ni < 2; ni++)                                                     \
        acc[mi][ni] = __builtin_amdgcn_mfma_scale_f32_32x32x64_f8f6f4(                   \
            af[mi], bf[ni], acc[mi][ni], 0, 0, 0, 0x7F7F7F7F, 0, 0x7F7F7F7F);            \
  } while (0)

  ISSUE(0, 0);
  ISSUE(1, 64);
#pragma unroll
  for (int k = 0; k < KIT; k++) {
    const int cur = k % 3;
    if (k < KIT - 2) {
      ISSUE((k + 2) % 3, (k + 2) * 64);
      __builtin_amdgcn_s_waitcnt(WAITCNT_VM8);
    } else if (k == KIT - 2) {
      __builtin_amdgcn_s_waitcnt(WAITCNT_VM4);
    } else {
      __builtin_amdgcn_s_waitcnt(WAITCNT_VM0);
    }
    __builtin_amdgcn_sched_barrier(0);
    __builtin_amdgcn_s_barrier();
    COMPUTE(cur);
    if (k < KIT - 1) {
      __builtin_amdgcn_s_barrier();
      __builtin_amdgcn_sched_barrier(0);
    }
  }

#undef ISSUE
#undef COMPUTE

  // ---- fused epilogue (LDS ring reused as tileE; all staging reads done) ----
  // 32x32 C/D layout: col = lane&31, row = (reg&3) + 8*(reg>>2) + 4*(lane>>5).
  float* tileE   = (float*)lds;                 // [128][129] f32 (66048 B)
  float* colpart = (float*)(lds + 66048);       // [2][128]       (1024 B)
  __syncthreads();

  // Phase 1: exp, col partial sums, numerator extraction (from registers, f32).
  {
    float ev0 = 0.f, ev1 = 0.f;
#pragma unroll
    for (int mi = 0; mi < 2; mi++)
#pragma unroll
      for (int ni = 0; ni < 2; ni++) {
        const int col = wc * 64 + ni * 32 + (lane & 31);
#pragma unroll
        for (int i = 0; i < 16; i++) {
          const int row = wr * 64 + mi * 32 + (i & 3) + 8 * (i >> 2) + 4 * (lane >> 5);
          const float v = acc[mi][ni][i] * OUT_SCALE;
          const float ev = __expf(v);
          tileE[row * 129 + col] = ev;
          if (ni == 0) ev0 += ev; else ev1 += ev;
          const int D = (gc + col - gr - row) & (NROWS - 1);
          if (D == 4 || D == 12) num_store(NUM, gr + row, D, v);
          if (ti != tj && (D == 2044 || D == 2036)) num_store(NUM, gc + col, 2048 - D, v);
        }
      }
    ev0 += __shfl_xor(ev0, 32, 64);
    ev1 += __shfl_xor(ev1, 32, 64);
    if (lane < 32) {
      colpart[wr * 128 + wc * 64 + (lane & 31)] = ev0;        // col sums, half wr
      colpart[wr * 128 + wc * 64 + 32 + (lane & 31)] = ev1;
    }
  }
  __syncthreads();

  // Phase 2a: window sums (256 threads -> 128 main + 128 mirror).
  if (tid < 128) {
    const int R = gr + tid;
#pragma unroll
    for (int k = 0; k < 6; k++) {
      const int aa = (R - 4 * k) & (NROWS - 1);
      if (aa % 12 < 4) {
        const int p2 = (aa / 12) * 4 + (aa % 12);
        const int csel = aa & 3;
        const int j0 = ((gc >> 2) - (aa >> 2)) & 511;
        float w = 0.f;
#pragma unroll
        for (int i2 = 0; i2 < 32; i2++) {
          const int j = j0 + i2;
          if (j < 160 || j >= 512) w += tileE[tid * 129 + 4 * i2 + csel];
        }
        atomicAdd(&WS[p2 * 6 + k], w);
      }
    }
  } else if (ti != tj) {
    const int col = tid - 128;
    const int R = gc + col;
#pragma unroll
    for (int k = 0; k < 6; k++) {
      const int aa = (R - 4 * k) & (NROWS - 1);
      if (aa % 12 < 4) {
        const int p2 = (aa / 12) * 4 + (aa % 12);
        const int csel = aa & 3;
        const int j0 = ((gr >> 2) - (aa >> 2)) & 511;
        float w = 0.f;
#pragma unroll
        for (int i2 = 0; i2 < 32; i2++) {
          const int j = j0 + i2;
          if (j < 160 || j >= 512) w += tileE[(4 * i2 + csel) * 129 + col];
        }
        atomicAdd(&WS[p2 * 6 + k], w);
      }
    }
  }

  // Phase 2b: T sums (row sums off-diagonal; col sums always, via colpart).
  if (tid < 128) {
    if (ti != tj) {
      float rs = 0.f;
#pragma unroll 8
      for (int c2 = 0; c2 < 128; c2++) rs += tileE[tid * 129 + c2];
      atomicAdd(&T[gr + tid], rs);
    }
  } else {
    const int c2 = tid - 128;
    atomicAdd(&T[gc + c2], colpart[c2] + colpart[128 + c2]);
  }
}

// ---- Kernel 3A: finisher. 19 blocks; Ds = T - WS; loss terms from NUM. ----
__global__ __launch_bounds__(256) void k_finalA(const float* __restrict__ NUM,
                                                const float* __restrict__ WS,
                                                const float* __restrict__ T,
                                                float* __restrict__ out) {
  const int pa[7] = {0, 1, 0, 3, 4, 1, 2};
  const int pb[7] = {1, 2, 3, 4, 5, 4, 5};
  const int idx = blockIdx.x * 256 + threadIdx.x;
  float s = 0.f;
  if (idx < NACT * 7) {
    const int p = idx / 7;
    const int q = idx - p * 7;
    const int a0 = 12 * (p >> 2) + (p & 3);
    const int ra = (a0 + 4 * pa[q]) & (NROWS - 1);
    const int rb = (a0 + 4 * pb[q]) & (NROWS - 1);
    const float dsA = T[ra] - WS[p * 6 + pa[q]];
    const float dsB = T[rb] - WS[p * 6 + pb[q]];
    const float num = NUM[idx];
    const float en = __expf(num);
    s = __logf(en + dsA) + __logf(en + dsB) - 2.f * num;
  }
#pragma unroll
  for (int off = 32; off > 0; off >>= 1) s += __shfl_down(s, off, 64);
  if ((threadIdx.x & 63) == 0) atomicAdd(out, s * (1.0f / (6.0f * 512.0f)));
}

// ------------- Path B kernels (fallback when ws is small; fp32 S) -------------
__global__ __launch_bounds__(256) void k_normconv(const float* __restrict__ X,
                                                  unsigned short* __restrict__ Y) {
  const int row = blockIdx.x;
  const float4* xr = (const float4*)(X + (size_t)row * DIM);
  float4 v[4];
  float s = 0.f;
#pragma unroll
  for (int t = 0; t < 4; t++) {
    float4 w = xr[threadIdx.x + t * 256];
    v[t] = w;
    s += w.x * w.x + w.y * w.y + w.z * w.z + w.w * w.w;
  }
#pragma unroll
  for (int off = 32; off > 0; off >>= 1) s += __shfl_down(s, off, 64);
  __shared__ float wsum[4];
  if ((threadIdx.x & 63) == 0) wsum[threadIdx.x >> 6] = s;
  __syncthreads();
  const float total = wsum[0] + wsum[1] + wsum[2] + wsum[3];
  const float inv = 1.0f / fmaxf(sqrtf(total), 1e-30f);
  ushort4* yr = (ushort4*)(Y + (size_t)row * DIM);
#pragma unroll
  for (int t = 0; t < 4; t++) {
    float4 w = v[t];
    ushort4 o;
    o.x = f32_to_bf16(w.x * inv);
    o.y = f32_to_bf16(w.y * inv);
    o.z = f32_to_bf16(w.z * inv);
    o.w = f32_to_bf16(w.w * inv);
    yr[threadIdx.x + t * 256] = o;
  }
}

__global__ __launch_bounds__(256) void k_gemm(const unsigned short* __restrict__ Y,
                                              float* __restrict__ S) {
  __shared__ __attribute__((aligned(16))) unsigned short sA[128 * 32];
  __shared__ __attribute__((aligned(16))) unsigned short sB[128 * 32];
  const int tid  = threadIdx.x;
  const int lane = tid & 63;
  const int wave = tid >> 6;
  const int wr = wave >> 1;
  const int wc = wave & 1;
  const int row0 = blockIdx.y * 128;
  const int col0 = blockIdx.x * 128;

  floatx4 zero = {0.f, 0.f, 0.f, 0.f};
  floatx4 acc[4][4];
#pragma unroll
  for (int i = 0; i < 4; i++)
#pragma unroll
    for (int j = 0; j < 4; j++) acc[i][j] = zero;

  const int sr = tid >> 2;
  const int sc = (tid & 3) * 8;
  const unsigned short* gA0 = Y + (size_t)(row0 + sr) * DIM + sc;
  const unsigned short* gA1 = gA0 + (size_t)64 * DIM;
  const unsigned short* gB0 = Y + (size_t)(col0 + sr) * DIM + sc;
  const unsigned short* gB1 = gB0 + (size_t)64 * DIM;

  const int fr = lane & 15;
  const int fc = (lane >> 4) * 8;

  for (int k0 = 0; k0 < DIM; k0 += 32) {
    __builtin_amdgcn_global_load_lds(
        (const __attribute__((address_space(1))) void*)(gA0 + k0),
        (__attribute__((address_space(3))) void*)(sA + tid * 8), 16, 0, 0);
    __builtin_amdgcn_global_load_lds(
        (const __attribute__((address_space(1))) void*)(gA1 + k0),
        (__attribute__((address_space(3))) void*)(sA + 2048 + tid * 8), 16, 0, 0);
    __builtin_amdgcn_global_load_lds(
        (const __attribute__((address_space(1))) void*)(gB0 + k0),
        (__attribute__((address_space(3))) void*)(sB + tid * 8), 16, 0, 0);
    __builtin_amdgcn_global_load_lds(
        (const __attribute__((address_space(1))) void*)(gB1 + k0),
        (__attribute__((address_space(3))) void*)(sB + 2048 + tid * 8), 16, 0, 0);
    __syncthreads();

    shortx8 af[4], bf[4];
#pragma unroll
    for (int mi = 0; mi < 4; mi++)
      af[mi] = *(const shortx8*)(sA + (wr * 64 + mi * 16 + fr) * 32 + fc);
#pragma unroll
    for (int ni = 0; ni < 4; ni++)
      bf[ni] = *(const shortx8*)(sB + (wc * 64 + ni * 16 + fr) * 32 + fc);
#pragma unroll
    for (int mi = 0; mi < 4; mi++)
#pragma unroll
      for (int ni = 0; ni < 4; ni++)
        acc[mi][ni] = __builtin_amdgcn_mfma_f32_16x16x32_bf16(af[mi], bf[ni], acc[mi][ni], 0, 0, 0);
    __syncthreads();
  }

  const int cc  = lane & 15;
  const int cr4 = (lane >> 4) * 4;
#pragma unroll
  for (int mi = 0; mi < 4; mi++) {
    const int row = row0 + wr * 64 + mi * 16 + cr4;
#pragma unroll
    for (int ni = 0; ni < 4; ni++) {
      const int col = col0 + wc * 64 + ni * 16 + cc;
      float* dst = S + (size_t)row * NROWS + col;
#pragma unroll
      for (int r = 0; r < 4; r++) dst[(size_t)r * NROWS] = acc[mi][ni][r] * INV_TEMP;
    }
  }
}

__global__ __launch_bounds__(256) void k_rowsum(const float* __restrict__ S,
                                                float* __restrict__ T) {
  const int row = blockIdx.x;
  const float* sr = S + (size_t)row * NROWS;
  float s = 0.f;
  for (int b = threadIdx.x; b < NROWS; b += 256) s += __expf(sr[b]);
#pragma unroll
  for (int off = 32; off > 0; off >>= 1) s += __shfl_down(s, off, 64);
  __shared__ float wsum[4];
  if ((threadIdx.x & 63) == 0) wsum[threadIdx.x >> 6] = s;
  __syncthreads();
  if (threadIdx.x == 0) T[row] = wsum[0] + wsum[1] + wsum[2] + wsum[3];
}

__global__ __launch_bounds__(64) void k_dsum(const float* __restrict__ S,
                                             const float* __restrict__ T,
                                             float* __restrict__ Ds) {
  const int p = blockIdx.x;
  const int k = blockIdx.y;
  const int a = 12 * (p >> 2) + (p & 3);
  const int lane = threadIdx.x;
  const int row = (a + 4 * k) & (NROWS - 1);
  const int m = a >> 2;
  const int c = a & 3;
  const float4* sr4 = (const float4*)(S + (size_t)row * NROWS);
  float s = 0.f;
  {
    float4 v0 = sr4[(m + lane) & 511];
    float4 v1 = sr4[(m + 64 + lane) & 511];
    float e0 = c == 0 ? v0.x : c == 1 ? v0.y : c == 2 ? v0.z : v0.w;
    float e1 = c == 0 ? v1.x : c == 1 ? v1.y : c == 2 ? v1.z : v1.w;
    s += __expf(e0) + __expf(e1);
    if (lane < 32) {
      float4 v2 = sr4[(m + 128 + lane) & 511];
      float e2 = c == 0 ? v2.x : c == 1 ? v2.y : c == 2 ? v2.z : v2.w;
      s += __expf(e2);
    }
  }
#pragma unroll
  for (int off = 32; off > 0; off >>= 1) s += __shfl_down(s, off, 64);
  if (lane == 0) Ds[p * 6 + k] = T[row] - s;
}

__global__ __launch_bounds__(256) void k_final(const float* __restrict__ S,
                                               const float* __restrict__ Ds,
                                               float* __restrict__ out) {
  const int pa[7] = {0, 1, 0, 3, 4, 1, 2};
  const int pb[7] = {1, 2, 3, 4, 5, 4, 5};
  const int idx = blockIdx.x * 256 + threadIdx.x;
  float s = 0.f;
  if (idx < NACT * 7) {
    const int p = idx / 7;
    const int q = idx - p * 7;
    const int a0 = 12 * (p >> 2) + (p & 3);
    const int ra = (a0 + 4 * pa[q]) & (NROWS - 1);
    const int rb = (a0 + 4 * pb[q]) & (NROWS - 1);
    const float num = S[(size_t)ra * NROWS + rb];
    const float en = __expf(num);
    s = __logf(en + Ds[p * 6 + pa[q]]) + __logf(en + Ds[p * 6 + pb[q]]) - 2.f * num;
  }
#pragma unroll
  for (int off = 32; off > 0; off >>= 1) s += __shfl_down(s, off, 64);
  if ((threadIdx.x & 63) == 0) atomicAdd(out, s * (1.0f / (6.0f * 512.0f)));
}

extern "C" void kernel_launch(void* const* d_in, const int* in_sizes, int n_in,
                              void* d_out, int out_size, void* d_ws, size_t ws_size,
                              hipStream_t stream) {
  const float* X = (const float*)d_in[0];
  char* ws = (char*)d_ws;
  float* out = (float*)d_out;

  const size_t pOff = (size_t)32 * 1024 * 1024;
  const size_t needA = pOff + 8192 + 24576 + 24576;   // T + WS + NUM

  if (ws_size >= needA) {
    unsigned char* Yq = (unsigned char*)ws;            // 8 MB fp8
    float* T   = (float*)(ws + pOff);                  // 2048 f32
    float* WS  = (float*)(ws + pOff + 8192);           // 4104 f32 window sums
    float* NUM = (float*)(ws + pOff + 8192 + 24576);   // 4788 f32 pair numerators
    hipLaunchKernelGGL(k_normconv_fp8, dim3(NROWS), dim3(256), 0, stream, X, Yq, T, WS, out);
    hipLaunchKernelGGL(k_gemm_full, dim3(NTILE128), dim3(256), 0, stream, Yq, T, WS, NUM);
    hipLaunchKernelGGL(k_finalA, dim3((NACT * 7 + 255) / 256), dim3(256), 0, stream,
                       NUM, WS, T, out);
  } else {
    unsigned short* Y = (unsigned short*)ws;                      // 16 MB bf16
    float* S = (float*)(ws + (size_t)16 * 1024 * 1024);           // 16 MB fp32
    float* T  = (float*)(ws + pOff);
    float* Ds = (float*)(ws + pOff + 8192);
    hipMemsetAsync(out, 0, sizeof(float), stream);
    hipLaunchKernelGGL(k_normconv, dim3(NROWS), dim3(256), 0, stream, X, Y);
    hipLaunchKernelGGL(k_gemm, dim3(16, 16), dim3(256), 0, stream, Y, S);
    hipLaunchKernelGGL(k_rowsum, dim3(NROWS), dim3(256), 0, stream, S, T);
    hipLaunchKernelGGL(k_dsum, dim3(NACT, 6), dim3(64), 0, stream, S, T, Ds);
    hipLaunchKernelGGL(k_final, dim3((NACT * 7 + 255) / 256), dim3(256), 0, stream, S, Ds, out);
  }
}

// Round 10
// 108.106 us; speedup vs baseline: 2.4666x; 2.4666x over previous
//
#include <hip/hip_runtime.h>
#include <hip/hip_bf16.h>
#include <stdint.h>

#define NROWS 2048
#define DIM   4096
#define NACT  684
#define INV_TEMP 10.0f
#define NPANEL 32        // 2048/64 row panels
#define NTILE64 528      // 32*33/2 upper-triangle 64x64 tiles
#define NK 64            // DIM / 64 K-steps
#define FP8_SCALE 16.0f  // Y stored as fp8(y*16); dot = 256*cos
#define OUT_SCALE (INV_TEMP / 256.0f)

// s_waitcnt immediates (gfx9/CDNA: vmcnt[3:0]@0, expcnt@4, lgkmcnt@8, vmcnt[5:4]@14)
#define WAITCNT_VM0   0x0F70
#define WAITCNT_VM4   0x0F74
#define WAITCNT_VM8   0x0F78

typedef __attribute__((ext_vector_type(4))) float floatx4;
typedef __attribute__((ext_vector_type(16))) float floatx16;
typedef __attribute__((ext_vector_type(4))) int intx4;
typedef __attribute__((ext_vector_type(8))) int intx8;
typedef __attribute__((ext_vector_type(8))) short shortx8;
typedef __attribute__((ext_vector_type(8))) unsigned short ushortx8;

static __device__ __forceinline__ unsigned short f32_to_bf16(float f) {
  union { float f; unsigned int u; } v; v.f = f;
  unsigned int u = v.u;
  unsigned int r = u + 0x7fffu + ((u >> 16) & 1u);
  return (unsigned short)(r >> 16);
}
static __device__ __forceinline__ float bf16_to_f32(unsigned short u) {
  union { unsigned int u; float f; } v; v.u = ((unsigned int)u) << 16;
  return v.f;
}
static __device__ __forceinline__ float f16_to_f32(unsigned short u) {
  union { unsigned short u; _Float16 h; } v; v.u = u;
  return (float)v.h;
}

// Pair tables: pa/pb per q; col-row delta = 4*(pb-pa) in {4,12}.
static __device__ __forceinline__ void num_store(float* __restrict__ NUM, int R, int delta,
                                                 float v) {
  if (delta == 4) {
    const int qs[4]  = {0, 1, 3, 4};
    const int pas[4] = {0, 1, 3, 4};
#pragma unroll
    for (int u = 0; u < 4; u++) {
      const int aa = (R - 4 * pas[u]) & (NROWS - 1);
      if (aa % 12 < 4) NUM[((aa / 12) * 4 + (aa % 12)) * 7 + qs[u]] = v;
    }
  } else {
    const int qs[3]  = {2, 5, 6};
    const int pas[3] = {0, 1, 2};
#pragma unroll
    for (int u = 0; u < 3; u++) {
      const int aa = (R - 4 * pas[u]) & (NROWS - 1);
      if (aa % 12 < 4) NUM[((aa / 12) * 4 + (aa % 12)) * 7 + qs[u]] = v;
    }
  }
}

// Supertile map: 32x32 panel grid in 8x8-panel quads; 10 upper-tri supertiles
// (diag=36 tiles, off=64), enumerated in an adjacency-preserving order. XCD x owns
// global sequence [66x, 66x+66) -> per-XCD panel footprint ~16 panels (~4MB = L2).
// Bijective by construction (prefix sums cover [0,528)).
static __device__ __forceinline__ void tile_map(int s, int* ti_out, int* tj_out) {
  const int pre[10] = {0, 36, 100, 136, 200, 236, 300, 336, 400, 464};
  const int str[10] = {0, 0, 1, 1, 2, 2, 3, 0, 0, 1};
  const int stc[10] = {0, 1, 1, 2, 2, 3, 3, 3, 2, 3};
  int g = 0;
#pragma unroll
  for (int i = 1; i < 10; i++)
    if (s >= pre[i]) g = i;
  int off = s - pre[g];
  int r, c;
  if (str[g] == stc[g]) {        // diagonal supertile: 8x8 upper-tri (36)
    r = 0;
    while (off >= 8 - r) { off -= 8 - r; r++; }
    c = r + off;
  } else {                        // off-diagonal: full 8x8 (64)
    r = off >> 3;
    c = off & 7;
  }
  *ti_out = str[g] * 8 + r;
  *tj_out = stc[g] * 8 + c;
}

// ------- Kernel 1A: per-row L2 norm + fp8 e4m3 convert (y*16); zeroes T/WS/out -------
__global__ __launch_bounds__(256) void k_normconv_fp8(const float* __restrict__ X,
                                                      unsigned char* __restrict__ Yq,
                                                      float* __restrict__ T,
                                                      float* __restrict__ WS,
                                                      float* __restrict__ out) {
  const int row = blockIdx.x;
  if (threadIdx.x == 0) T[row] = 0.f;
  if (row == 0 && threadIdx.x == 64) *out = 0.f;
  if (row < NACT && threadIdx.x >= 192 && threadIdx.x < 198)
    WS[row * 6 + (threadIdx.x - 192)] = 0.f;
  const float4* xr = (const float4*)(X + (size_t)row * DIM);
  float4 v[4];
  float s = 0.f;
#pragma unroll
  for (int t = 0; t < 4; t++) {
    float4 w = xr[threadIdx.x + t * 256];
    v[t] = w;
    s += w.x * w.x + w.y * w.y + w.z * w.z + w.w * w.w;
  }
#pragma unroll
  for (int off = 32; off > 0; off >>= 1) s += __shfl_down(s, off, 64);
  __shared__ float wsum[4];
  if ((threadIdx.x & 63) == 0) wsum[threadIdx.x >> 6] = s;
  __syncthreads();
  const float total = wsum[0] + wsum[1] + wsum[2] + wsum[3];
  const float sc = FP8_SCALE / fmaxf(sqrtf(total), 1e-30f);
  unsigned int* yr = (unsigned int*)(Yq + (size_t)row * DIM);
#pragma unroll
  for (int t = 0; t < 4; t++) {
    float4 w = v[t];
    unsigned int r0 = __builtin_amdgcn_cvt_pk_fp8_f32(w.x * sc, w.y * sc, 0, false);
    r0 = __builtin_amdgcn_cvt_pk_fp8_f32(w.z * sc, w.w * sc, r0, true);
    yr[threadIdx.x + t * 256] = r0;
  }
}

// ------- Kernel 2A: R6-verified 64x64 full-K MX-fp8 GEMM + fused T/WS/NUM epilogue -------
// ONLY change vs the verified R6 kernel (47.5us, passed): block->tile map is now the
// supertile map (per-XCD 2D-compact footprint ~4MB -> L2-resident panels instead of L3).
// Everything else byte-identical: 6-stage ring, 2 K-steps/phase, counted vmcnt(8/4/0),
// setprio around MFMA, register epilogue.
__global__ __launch_bounds__(256) void k_gemm_full(const unsigned char* __restrict__ Yq,
                                                   float* __restrict__ T,
                                                   float* __restrict__ WS,
                                                   float* __restrict__ NUM) {
  __shared__ __attribute__((aligned(16))) unsigned char lds[6 * 8192];
  const int bid0 = blockIdx.x;
  const int s = (bid0 & 7) * 66 + (bid0 >> 3);   // XCD-contiguous global sequence
  int ti, tj;
  tile_map(s, &ti, &tj);
  const int gr = ti * 64;
  const int gc = tj * 64;

  const int tid  = threadIdx.x;
  const int lane = tid & 63;
  const int wave = tid >> 6;
  const int wr = wave >> 1;
  const int wc = wave & 1;

  floatx16 acc = {0.f, 0.f, 0.f, 0.f, 0.f, 0.f, 0.f, 0.f,
                  0.f, 0.f, 0.f, 0.f, 0.f, 0.f, 0.f, 0.f};

  // staging: thread t covers 16 B: row r2 = t>>2 (0..63), chunk c16 = t&3.
  // Source column pre-swizzled (linear LDS dest + inverse-swizzled source + swizzled read).
  const int r2  = tid >> 2;
  const int c16 = tid & 3;
  const unsigned int swst = (unsigned)(((r2 >> 1) & 3) << 4);
  const unsigned int colst = ((unsigned)(c16 << 4)) ^ swst;
  const unsigned char* gA = Yq + (size_t)(gr + r2) * DIM + colst;
  const unsigned char* gB = Yq + (size_t)(gc + r2) * DIM + colst;

#define ISSUE(st, koff)                                                                  \
  do {                                                                                   \
    __builtin_amdgcn_global_load_lds(                                                    \
        (const __attribute__((address_space(1))) void*)(gA + (koff)),                    \
        (__attribute__((address_space(3))) void*)(lds + (st) * 8192 + tid * 16),         \
        16, 0, 0);                                                                       \
    __builtin_amdgcn_global_load_lds(                                                    \
        (const __attribute__((address_space(1))) void*)(gB + (koff)),                    \
        (__attribute__((address_space(3))) void*)(lds + (st) * 8192 + 4096 + tid * 16),  \
        16, 0, 0);                                                                       \
  } while (0)

#define COMPUTE(st)                                                                      \
  do {                                                                                   \
    const unsigned char* bA = lds + (st) * 8192;                                         \
    const unsigned char* bB = bA + 4096;                                                 \
    const unsigned int c0 = (unsigned)((lane >> 5) << 5);                                \
    const int rA = wr * 32 + (lane & 31);                                                \
    const int rB = wc * 32 + (lane & 31);                                                \
    const unsigned int swA = (unsigned)(((rA >> 1) & 3) << 4);                           \
    const unsigned int swB = (unsigned)(((rB >> 1) & 3) << 4);                           \
    const unsigned char* baseA = bA + rA * 64;                                           \
    const unsigned char* baseB = bB + rB * 64;                                           \
    intx4 alo = *(const intx4*)(baseA + (c0 ^ swA));                                     \
    intx4 ahi = *(const intx4*)(baseA + ((c0 ^ swA) ^ 16u));                             \
    intx4 blo = *(const intx4*)(baseB + (c0 ^ swB));                                     \
    intx4 bhi = *(const intx4*)(baseB + ((c0 ^ swB) ^ 16u));                             \
    intx8 af, bf;                                                                        \
    af[0] = alo[0]; af[1] = alo[1]; af[2] = alo[2]; af[3] = alo[3];                      \
    af[4] = ahi[0]; af[5] = ahi[1]; af[6] = ahi[2]; af[7] = ahi[3];                      \
    bf[0] = blo[0]; bf[1] = blo[1]; bf[2] = blo[2]; bf[3] = blo[3];                      \
    bf[4] = bhi[0]; bf[5] = bhi[1]; bf[6] = bhi[2]; bf[7] = bhi[3];                      \
    acc = __builtin_amdgcn_mfma_scale_f32_32x32x64_f8f6f4(                               \
        af, bf, acc, 0, 0, 0, 0x7F7F7F7F, 0, 0x7F7F7F7F);                                \
  } while (0)

  // Prologue: 4 K-steps in flight (8 loads).
  ISSUE(0, 0);
  ISSUE(1, 64);
  ISSUE(2, 128);
  ISSUE(3, 192);
#pragma unroll
  for (int p = 0; p < 32; p++) {
    const int a = (2 * p) % 6;            // compile-time after full unroll
    if (p < 30) {
      const int na = (2 * p + 4) % 6;
      ISSUE(na, (2 * p + 4) * 64);
      ISSUE(na + 1, (2 * p + 5) * 64);
      __builtin_amdgcn_s_waitcnt(WAITCNT_VM8);   // 12 outstanding -> drain oldest pair
    } else if (p == 30) {
      __builtin_amdgcn_s_waitcnt(WAITCNT_VM4);
    } else {
      __builtin_amdgcn_s_waitcnt(WAITCNT_VM0);
    }
    __builtin_amdgcn_sched_barrier(0);
    __builtin_amdgcn_s_barrier();
    __builtin_amdgcn_s_setprio(1);
    COMPUTE(a);
    COMPUTE(a + 1);
    __builtin_amdgcn_s_setprio(0);
    if (p < 31) {
      __builtin_amdgcn_s_barrier();
      __builtin_amdgcn_sched_barrier(0);
    }
  }

#undef ISSUE
#undef COMPUTE

  // ---- fused epilogue (LDS reused; sync guards last-stage readers) ----
  // 32x32 C/D layout: col = lane&31, row = (reg&3) + 8*(reg>>2) + 4*(lane>>5).
  float* tileE   = (float*)lds;                 // [64][65] float (16640 B)
  float* colpart = (float*)(lds + 16640);       // [2][64]        (512 B)
  __syncthreads();

  // Phase 1: exp, col partial sums, numerator extraction.
  {
    const int col = wc * 32 + (lane & 31);
    float evsum = 0.f;
#pragma unroll
    for (int i = 0; i < 16; i++) {
      const int row = wr * 32 + (i & 3) + 8 * (i >> 2) + 4 * (lane >> 5);
      const float v = acc[i] * OUT_SCALE;
      const float ev = __expf(v);
      tileE[row * 65 + col] = ev;
      evsum += ev;
      const int D = (gc + col - gr - row) & (NROWS - 1);
      if (D == 4 || D == 12) num_store(NUM, gr + row, D, v);
      if (ti != tj && (D == 2044 || D == 2036)) num_store(NUM, gc + col, 2048 - D, v);
    }
    evsum += __shfl_xor(evsum, 32, 64);
    if (lane < 32) colpart[wr * 64 + col] = evsum;   // wave-unique slot, no atomic
  }
  __syncthreads();

  // Phase 2: four parallel thread groups.
  if (tid < 64) {
    // main-orientation window sums: rows R = gr+tid, cols [gc, gc+64)
    const int R = gr + tid;
#pragma unroll
    for (int k = 0; k < 6; k++) {
      const int aa = (R - 4 * k) & (NROWS - 1);
      if (aa % 12 < 4) {
        const int p2 = (aa / 12) * 4 + (aa % 12);
        const int c = aa & 3;
        const int j0 = ((gc >> 2) - (aa >> 2)) & 511;
        float w = 0.f;
#pragma unroll
        for (int i2 = 0; i2 < 16; i2++) {
          const int j = j0 + i2;
          if (j < 160 || j >= 512) w += tileE[tid * 65 + 4 * i2 + c];
        }
        atomicAdd(&WS[p2 * 6 + k], w);
      }
    }
  } else if (tid < 128) {
    // mirror-orientation window sums: rows R = gc+col, cols [gr, gr+64)
    if (ti != tj) {
      const int col = tid - 64;
      const int R = gc + col;
#pragma unroll
      for (int k = 0; k < 6; k++) {
        const int aa = (R - 4 * k) & (NROWS - 1);
        if (aa % 12 < 4) {
          const int p2 = (aa / 12) * 4 + (aa % 12);
          const int c = aa & 3;
          const int j0 = ((gr >> 2) - (aa >> 2)) & 511;
          float w = 0.f;
#pragma unroll
          for (int i2 = 0; i2 < 16; i2++) {
            const int j = j0 + i2;
            if (j < 160 || j >= 512) w += tileE[(4 * i2 + c) * 65 + col];
          }
          atomicAdd(&WS[p2 * 6 + k], w);
        }
      }
    }
  } else if (tid < 192) {
    // row sums -> T[gr+r] (off-diagonal only; diagonal covered by col sums)
    if (ti != tj) {
      const int r = tid - 128;
      float rs = 0.f;
#pragma unroll 8
      for (int c = 0; c < 64; c++) rs += tileE[r * 65 + c];
      atomicAdd(&T[gr + r], rs);
    }
  } else {
    // col sums -> T[gc+c] (symmetry: column sum == mirrored row sum)
    const int c = tid - 192;
    atomicAdd(&T[gc + c], colpart[c] + colpart[64 + c]);
  }
}

// ---- Kernel 3A: finisher. 19 blocks; Ds = T - WS; loss terms from NUM. ----
__global__ __launch_bounds__(256) void k_finalA(const float* __restrict__ NUM,
                                                const float* __restrict__ WS,
                                                const float* __restrict__ T,
                                                float* __restrict__ out) {
  const int pa[7] = {0, 1, 0, 3, 4, 1, 2};
  const int pb[7] = {1, 2, 3, 4, 5, 4, 5};
  const int idx = blockIdx.x * 256 + threadIdx.x;
  float s = 0.f;
  if (idx < NACT * 7) {
    const int p = idx / 7;
    const int q = idx - p * 7;
    const int a0 = 12 * (p >> 2) + (p & 3);
    const int ra = (a0 + 4 * pa[q]) & (NROWS - 1);
    const int rb = (a0 + 4 * pb[q]) & (NROWS - 1);
    const float dsA = T[ra] - WS[p * 6 + pa[q]];
    const float dsB = T[rb] - WS[p * 6 + pb[q]];
    const float num = NUM[idx];
    const float en = __expf(num);
    s = __logf(en + dsA) + __logf(en + dsB) - 2.f * num;
  }
#pragma unroll
  for (int off = 32; off > 0; off >>= 1) s += __shfl_down(s, off, 64);
  if ((threadIdx.x & 63) == 0) atomicAdd(out, s * (1.0f / (6.0f * 512.0f)));
}

// ------------- Path B kernels (fallback when ws is small; fp32 S) -------------
__global__ __launch_bounds__(256) void k_normconv(const float* __restrict__ X,
                                                  unsigned short* __restrict__ Y) {
  const int row = blockIdx.x;
  const float4* xr = (const float4*)(X + (size_t)row * DIM);
  float4 v[4];
  float s = 0.f;
#pragma unroll
  for (int t = 0; t < 4; t++) {
    float4 w = xr[threadIdx.x + t * 256];
    v[t] = w;
    s += w.x * w.x + w.y * w.y + w.z * w.z + w.w * w.w;
  }
#pragma unroll
  for (int off = 32; off > 0; off >>= 1) s += __shfl_down(s, off, 64);
  __shared__ float wsum[4];
  if ((threadIdx.x & 63) == 0) wsum[threadIdx.x >> 6] = s;
  __syncthreads();
  const float total = wsum[0] + wsum[1] + wsum[2] + wsum[3];
  const float inv = 1.0f / fmaxf(sqrtf(total), 1e-30f);
  ushort4* yr = (ushort4*)(Y + (size_t)row * DIM);
#pragma unroll
  for (int t = 0; t < 4; t++) {
    float4 w = v[t];
    ushort4 o;
    o.x = f32_to_bf16(w.x * inv);
    o.y = f32_to_bf16(w.y * inv);
    o.z = f32_to_bf16(w.z * inv);
    o.w = f32_to_bf16(w.w * inv);
    yr[threadIdx.x + t * 256] = o;
  }
}

__global__ __launch_bounds__(256) void k_gemm(const unsigned short* __restrict__ Y,
                                              float* __restrict__ S) {
  __shared__ __attribute__((aligned(16))) unsigned short sA[128 * 32];
  __shared__ __attribute__((aligned(16))) unsigned short sB[128 * 32];
  const int tid  = threadIdx.x;
  const int lane = tid & 63;
  const int wave = tid >> 6;
  const int wr = wave >> 1;
  const int wc = wave & 1;
  const int row0 = blockIdx.y * 128;
  const int col0 = blockIdx.x * 128;

  floatx4 zero = {0.f, 0.f, 0.f, 0.f};
  floatx4 acc[4][4];
#pragma unroll
  for (int i = 0; i < 4; i++)
#pragma unroll
    for (int j = 0; j < 4; j++) acc[i][j] = zero;

  const int sr = tid >> 2;
  const int sc = (tid & 3) * 8;
  const unsigned short* gA0 = Y + (size_t)(row0 + sr) * DIM + sc;
  const unsigned short* gA1 = gA0 + (size_t)64 * DIM;
  const unsigned short* gB0 = Y + (size_t)(col0 + sr) * DIM + sc;
  const unsigned short* gB1 = gB0 + (size_t)64 * DIM;

  const int fr = lane & 15;
  const int fc = (lane >> 4) * 8;

  for (int k0 = 0; k0 < DIM; k0 += 32) {
    __builtin_amdgcn_global_load_lds(
        (const __attribute__((address_space(1))) void*)(gA0 + k0),
        (__attribute__((address_space(3))) void*)(sA + tid * 8), 16, 0, 0);
    __builtin_amdgcn_global_load_lds(
        (const __attribute__((address_space(1))) void*)(gA1 + k0),
        (__attribute__((address_space(3))) void*)(sA + 2048 + tid * 8), 16, 0, 0);
    __builtin_amdgcn_global_load_lds(
        (const __attribute__((address_space(1))) void*)(gB0 + k0),
        (__attribute__((address_space(3))) void*)(sB + tid * 8), 16, 0, 0);
    __builtin_amdgcn_global_load_lds(
        (const __attribute__((address_space(1))) void*)(gB1 + k0),
        (__attribute__((address_space(3))) void*)(sB + 2048 + tid * 8), 16, 0, 0);
    __syncthreads();

    shortx8 af[4], bf[4];
#pragma unroll
    for (int mi = 0; mi < 4; mi++)
      af[mi] = *(const shortx8*)(sA + (wr * 64 + mi * 16 + fr) * 32 + fc);
#pragma unroll
    for (int ni = 0; ni < 4; ni++)
      bf[ni] = *(const shortx8*)(sB + (wc * 64 + ni * 16 + fr) * 32 + fc);
#pragma unroll
    for (int mi = 0; mi < 4; mi++)
#pragma unroll
      for (int ni = 0; ni < 4; ni++)
        acc[mi][ni] = __builtin_amdgcn_mfma_f32_16x16x32_bf16(af[mi], bf[ni], acc[mi][ni], 0, 0, 0);
    __syncthreads();
  }

  const int cc  = lane & 15;
  const int cr4 = (lane >> 4) * 4;
#pragma unroll
  for (int mi = 0; mi < 4; mi++) {
    const int row = row0 + wr * 64 + mi * 16 + cr4;
#pragma unroll
    for (int ni = 0; ni < 4; ni++) {
      const int col = col0 + wc * 64 + ni * 16 + cc;
      float* dst = S + (size_t)row * NROWS + col;
#pragma unroll
      for (int r = 0; r < 4; r++) dst[(size_t)r * NROWS] = acc[mi][ni][r] * INV_TEMP;
    }
  }
}

__global__ __launch_bounds__(256) void k_rowsum(const float* __restrict__ S,
                                                float* __restrict__ T) {
  const int row = blockIdx.x;
  const float* sr = S + (size_t)row * NROWS;
  float s = 0.f;
  for (int b = threadIdx.x; b < NROWS; b += 256) s += __expf(sr[b]);
#pragma unroll
  for (int off = 32; off > 0; off >>= 1) s += __shfl_down(s, off, 64);
  __shared__ float wsum[4];
  if ((threadIdx.x & 63) == 0) wsum[threadIdx.x >> 6] = s;
  __syncthreads();
  if (threadIdx.x == 0) T[row] = wsum[0] + wsum[1] + wsum[2] + wsum[3];
}

__global__ __launch_bounds__(64) void k_dsum(const float* __restrict__ S,
                                             const float* __restrict__ T,
                                             float* __restrict__ Ds) {
  const int p = blockIdx.x;
  const int k = blockIdx.y;
  const int a = 12 * (p >> 2) + (p & 3);
  const int lane = threadIdx.x;
  const int row = (a + 4 * k) & (NROWS - 1);
  const int m = a >> 2;
  const int c = a & 3;
  const float4* sr4 = (const float4*)(S + (size_t)row * NROWS);
  float s = 0.f;
  {
    float4 v0 = sr4[(m + lane) & 511];
    float4 v1 = sr4[(m + 64 + lane) & 511];
    float e0 = c == 0 ? v0.x : c == 1 ? v0.y : c == 2 ? v0.z : v0.w;
    float e1 = c == 0 ? v1.x : c == 1 ? v1.y : c == 2 ? v1.z : v1.w;
    s += __expf(e0) + __expf(e1);
    if (lane < 32) {
      float4 v2 = sr4[(m + 128 + lane) & 511];
      float e2 = c == 0 ? v2.x : c == 1 ? v2.y : c == 2 ? v2.z : v2.w;
      s += __expf(e2);
    }
  }
#pragma unroll
  for (int off = 32; off > 0; off >>= 1) s += __shfl_down(s, off, 64);
  if (lane == 0) Ds[p * 6 + k] = T[row] - s;
}

__global__ __launch_bounds__(256) void k_final(const float* __restrict__ S,
                                               const float* __restrict__ Ds,
                                               float* __restrict__ out) {
  const int pa[7] = {0, 1, 0, 3, 4, 1, 2};
  const int pb[7] = {1, 2, 3, 4, 5, 4, 5};
  const int idx = blockIdx.x * 256 + threadIdx.x;
  float s = 0.f;
  if (idx < NACT * 7) {
    const int p = idx / 7;
    const int q = idx - p * 7;
    const int a0 = 12 * (p >> 2) + (p & 3);
    const int ra = (a0 + 4 * pa[q]) & (NROWS - 1);
    const int rb = (a0 + 4 * pb[q]) & (NROWS - 1);
    const float num = S[(size_t)ra * NROWS + rb];
    const float en = __expf(num);
    s = __logf(en + Ds[p * 6 + pa[q]]) + __logf(en + Ds[p * 6 + pb[q]]) - 2.f * num;
  }
#pragma unroll
  for (int off = 32; off > 0; off >>= 1) s += __shfl_down(s, off, 64);
  if ((threadIdx.x & 63) == 0) atomicAdd(out, s * (1.0f / (6.0f * 512.0f)));
}

extern "C" void kernel_launch(void* const* d_in, const int* in_sizes, int n_in,
                              void* d_out, int out_size, void* d_ws, size_t ws_size,
                              hipStream_t stream) {
  const float* X = (const float*)d_in[0];
  char* ws = (char*)d_ws;
  float* out = (float*)d_out;

  const size_t pOff = (size_t)32 * 1024 * 1024;
  const size_t needA = pOff + 8192 + 24576 + 24576;   // T + WS + NUM

  if (ws_size >= needA) {
    unsigned char* Yq = (unsigned char*)ws;            // 8 MB fp8
    float* T   = (float*)(ws + pOff);                  // 2048 f32
    float* WS  = (float*)(ws + pOff + 8192);           // 4104 f32 window sums
    float* NUM = (float*)(ws + pOff + 8192 + 24576);   // 4788 f32 pair numerators
    hipLaunchKernelGGL(k_normconv_fp8, dim3(NROWS), dim3(256), 0, stream, X, Yq, T, WS, out);
    hipLaunchKernelGGL(k_gemm_full, dim3(NTILE64), dim3(256), 0, stream, Yq, T, WS, NUM);
    hipLaunchKernelGGL(k_finalA, dim3((NACT * 7 + 255) / 256), dim3(256), 0, stream,
                       NUM, WS, T, out);
  } else {
    unsigned short* Y = (unsigned short*)ws;                      // 16 MB bf16
    float* S = (float*)(ws + (size_t)16 * 1024 * 1024);           // 16 MB fp32
    float* T  = (float*)(ws + pOff);
    float* Ds = (float*)(ws + pOff + 8192);
    hipMemsetAsync(out, 0, sizeof(float), stream);
    hipLaunchKernelGGL(k_normconv, dim3(NROWS), dim3(256), 0, stream, X, Y);
    hipLaunchKernelGGL(k_gemm, dim3(16, 16), dim3(256), 0, stream, Y, S);
    hipLaunchKernelGGL(k_rowsum, dim3(NROWS), dim3(256), 0, stream, S, T);
    hipLaunchKernelGGL(k_dsum, dim3(NACT, 6), dim3(64), 0, stream, S, T, Ds);
    hipLaunchKernelGGL(k_final, dim3((NACT * 7 + 255) / 256), dim3(256), 0, stream, S, Ds, out);
  }
}

// Round 11
// 107.456 us; speedup vs baseline: 2.4815x; 1.0060x over previous
//
#include <hip/hip_runtime.h>
#include <hip/hip_bf16.h>
#include <stdint.h>

#define NROWS 2048
#define DIM   4096
#define NACT  684
#define INV_TEMP 10.0f
#define NTILE128 136     // 16*17/2 upper-triangle 128x128 tiles
#define KSPLIT 2
#define KSEG  2048       // DIM / KSPLIT
#define KIT   32         // KSEG / 64 (MX K-step = 64)
#define FP8_SCALE 16.0f  // Y stored as fp8(y*16); dot = 256*cos
#define PART_SCALE (1.0f / 256.0f)

// s_waitcnt immediates (gfx9/CDNA: vmcnt[3:0]@0, expcnt@4, lgkmcnt@8, vmcnt[5:4]@14)
#define WAITCNT_VM0   0x0F70
#define WAITCNT_VM4   0x0F74
#define WAITCNT_VM8   0x0F78

typedef __attribute__((ext_vector_type(4))) float floatx4;
typedef __attribute__((ext_vector_type(16))) float floatx16;
typedef __attribute__((ext_vector_type(4))) int intx4;
typedef __attribute__((ext_vector_type(8))) int intx8;
typedef __attribute__((ext_vector_type(8))) short shortx8;
typedef __attribute__((ext_vector_type(8))) unsigned short ushortx8;

static __device__ __forceinline__ unsigned short f32_to_bf16(float f) {
  union { float f; unsigned int u; } v; v.f = f;
  unsigned int u = v.u;
  unsigned int r = u + 0x7fffu + ((u >> 16) & 1u);
  return (unsigned short)(r >> 16);
}
static __device__ __forceinline__ float bf16_to_f32(unsigned short u) {
  union { unsigned int u; float f; } v; v.u = ((unsigned int)u) << 16;
  return v.f;
}
static __device__ __forceinline__ float f16_to_f32(unsigned short u) {
  union { unsigned short u; _Float16 h; } v; v.u = u;
  return (float)v.h;
}

// Pair tables: pa/pb per q; col-row delta = 4*(pb-pa) in {4,12}.
static __device__ __forceinline__ void num_store(float* __restrict__ NUM, int R, int delta,
                                                 float v) {
  if (delta == 4) {
    const int qs[4]  = {0, 1, 3, 4};
    const int pas[4] = {0, 1, 3, 4};
#pragma unroll
    for (int u = 0; u < 4; u++) {
      const int aa = (R - 4 * pas[u]) & (NROWS - 1);
      if (aa % 12 < 4) NUM[((aa / 12) * 4 + (aa % 12)) * 7 + qs[u]] = v;
    }
  } else {
    const int qs[3]  = {2, 5, 6};
    const int pas[3] = {0, 1, 2};
#pragma unroll
    for (int u = 0; u < 3; u++) {
      const int aa = (R - 4 * pas[u]) & (NROWS - 1);
      if (aa % 12 < 4) NUM[((aa / 12) * 4 + (aa % 12)) * 7 + qs[u]] = v;
    }
  }
}

// ------- Kernel 1A: per-row L2 norm + fp8 e4m3 convert (y*16); zeroes T/WS/out -------
__global__ __launch_bounds__(256) void k_normconv_fp8(const float* __restrict__ X,
                                                      unsigned char* __restrict__ Yq,
                                                      float* __restrict__ T,
                                                      float* __restrict__ WS,
                                                      float* __restrict__ out) {
  const int row = blockIdx.x;
  if (threadIdx.x == 0) T[row] = 0.f;
  if (row == 0 && threadIdx.x == 64) *out = 0.f;
  if (row < NACT && threadIdx.x >= 192 && threadIdx.x < 198)
    WS[row * 6 + (threadIdx.x - 192)] = 0.f;
  const float4* xr = (const float4*)(X + (size_t)row * DIM);
  float4 v[4];
  float s = 0.f;
#pragma unroll
  for (int t = 0; t < 4; t++) {
    float4 w = xr[threadIdx.x + t * 256];
    v[t] = w;
    s += w.x * w.x + w.y * w.y + w.z * w.z + w.w * w.w;
  }
#pragma unroll
  for (int off = 32; off > 0; off >>= 1) s += __shfl_down(s, off, 64);
  __shared__ float wsum[4];
  if ((threadIdx.x & 63) == 0) wsum[threadIdx.x >> 6] = s;
  __syncthreads();
  const float total = wsum[0] + wsum[1] + wsum[2] + wsum[3];
  const float sc = FP8_SCALE / fmaxf(sqrtf(total), 1e-30f);
  unsigned int* yr = (unsigned int*)(Yq + (size_t)row * DIM);
#pragma unroll
  for (int t = 0; t < 4; t++) {
    float4 w = v[t];
    unsigned int r0 = __builtin_amdgcn_cvt_pk_fp8_f32(w.x * sc, w.y * sc, 0, false);
    r0 = __builtin_amdgcn_cvt_pk_fp8_f32(w.z * sc, w.w * sc, r0, true);
    yr[threadIdx.x + t * 256] = r0;
  }
}

// ------- Kernel 2A: 128x128-tile split-K(2) MX-fp8 GEMM (R8-verified, unchanged) -------
// 272 blocks fill all CUs at 3 blocks/CU; total staged bytes 139 MB (vs 264 MB for 64^2
// tiles) against the measured ~22 GB/s/CU ingest ceiling. Partials: bf16 col-major.
__global__ __launch_bounds__(256) void k_gemm_mx(const unsigned char* __restrict__ Yq,
                                                 unsigned short* __restrict__ P) {
  __shared__ __attribute__((aligned(16))) unsigned char lds[3 * 16384];
  // bijective XCD swizzle (272 = 8*34): consecutive logical jobs share an XCD.
  const int bid0 = blockIdx.x;
  const int bid = (bid0 & 7) * 34 + (bid0 >> 3);
  const int kz = bid & 1;
  const int t  = bid >> 1;
  int ti = 0, rem = t;
  while (rem >= 16 - ti) { rem -= 16 - ti; ti++; }
  const int tj = ti + rem;
  const int row0 = ti * 128;
  const int col0 = tj * 128;
  const int kbase = kz * KSEG;

  const int tid  = threadIdx.x;
  const int lane = tid & 63;
  const int wave = tid >> 6;
  const int wr = wave >> 1;
  const int wc = wave & 1;

  floatx16 zero = {0.f, 0.f, 0.f, 0.f, 0.f, 0.f, 0.f, 0.f,
                   0.f, 0.f, 0.f, 0.f, 0.f, 0.f, 0.f, 0.f};
  floatx16 acc[2][2];
#pragma unroll
  for (int i = 0; i < 2; i++)
#pragma unroll
    for (int j = 0; j < 2; j++) acc[i][j] = zero;

  // staging: thread t covers LDS bytes [16t,16t+16): row r2=t>>2, chunk t&3.
  // Source column pre-swizzled (linear dest + inverse-swizzled source + swizzled read).
  const int r2  = tid >> 2;
  const int c16 = tid & 3;
  const unsigned int swst = (unsigned)(((r2 >> 1) & 3) << 4);
  const unsigned int colst = ((unsigned)(c16 << 4)) ^ swst;
  const unsigned char* gA = Yq + (size_t)(row0 + r2) * DIM + kbase + colst;
  const unsigned char* gB = Yq + (size_t)(col0 + r2) * DIM + kbase + colst;

#define ISSUE(st, koff)                                                                  \
  do {                                                                                   \
    __builtin_amdgcn_global_load_lds(                                                    \
        (const __attribute__((address_space(1))) void*)(gA + (koff)),                    \
        (__attribute__((address_space(3))) void*)(lds + (st) * 16384 + tid * 16),        \
        16, 0, 0);                                                                       \
    __builtin_amdgcn_global_load_lds(                                                    \
        (const __attribute__((address_space(1))) void*)(gA + (size_t)64 * DIM + (koff)), \
        (__attribute__((address_space(3))) void*)(lds + (st) * 16384 + 4096 + tid * 16), \
        16, 0, 0);                                                                       \
    __builtin_amdgcn_global_load_lds(                                                    \
        (const __attribute__((address_space(1))) void*)(gB + (koff)),                    \
        (__attribute__((address_space(3))) void*)(lds + (st) * 16384 + 8192 + tid * 16), \
        16, 0, 0);                                                                       \
    __builtin_amdgcn_global_load_lds(                                                    \
        (const __attribute__((address_space(1))) void*)(gB + (size_t)64 * DIM + (koff)), \
        (__attribute__((address_space(3))) void*)(lds + (st) * 16384 + 12288 + tid * 16),\
        16, 0, 0);                                                                       \
  } while (0)

#define COMPUTE(st)                                                                      \
  do {                                                                                   \
    const unsigned char* bA = lds + (st) * 16384;                                        \
    const unsigned char* bB = bA + 8192;                                                 \
    const unsigned int c0 = (unsigned)((lane >> 5) << 5);                                \
    intx8 af[2], bf[2];                                                                  \
    _Pragma("unroll")                                                                    \
    for (int mi = 0; mi < 2; mi++) {                                                     \
      const int r = wr * 64 + mi * 32 + (lane & 31);                                     \
      const unsigned int sw = (unsigned)(((r >> 1) & 3) << 4);                           \
      const unsigned char* base = bA + r * 64;                                           \
      intx4 lo = *(const intx4*)(base + (c0 ^ sw));                                      \
      intx4 hi = *(const intx4*)(base + ((c0 ^ sw) ^ 16u));                              \
      intx8 v;                                                                           \
      v[0] = lo[0]; v[1] = lo[1]; v[2] = lo[2]; v[3] = lo[3];                            \
      v[4] = hi[0]; v[5] = hi[1]; v[6] = hi[2]; v[7] = hi[3];                            \
      af[mi] = v;                                                                        \
    }                                                                                    \
    _Pragma("unroll")                                                                    \
    for (int ni = 0; ni < 2; ni++) {                                                     \
      const int r = wc * 64 + ni * 32 + (lane & 31);                                     \
      const unsigned int sw = (unsigned)(((r >> 1) & 3) << 4);                           \
      const unsigned char* base = bB + r * 64;                                           \
      intx4 lo = *(const intx4*)(base + (c0 ^ sw));                                      \
      intx4 hi = *(const intx4*)(base + ((c0 ^ sw) ^ 16u));                              \
      intx8 v;                                                                           \
      v[0] = lo[0]; v[1] = lo[1]; v[2] = lo[2]; v[3] = lo[3];                            \
      v[4] = hi[0]; v[5] = hi[1]; v[6] = hi[2]; v[7] = hi[3];                            \
      bf[ni] = v;                                                                        \
    }                                                                                    \
    _Pragma("unroll")                                                                    \
    for (int mi = 0; mi < 2; mi++)                                                       \
      _Pragma("unroll")                                                                  \
      for (int ni = 0; ni < 2; ni++)                                                     \
        acc[mi][ni] = __builtin_amdgcn_mfma_scale_f32_32x32x64_f8f6f4(                   \
            af[mi], bf[ni], acc[mi][ni], 0, 0, 0, 0x7F7F7F7F, 0, 0x7F7F7F7F);            \
  } while (0)

  ISSUE(0, 0);
  ISSUE(1, 64);
#pragma unroll
  for (int k = 0; k < KIT; k++) {
    const int cur = k % 3;
    if (k < KIT - 2) {
      ISSUE((k + 2) % 3, (k + 2) * 64);
      __builtin_amdgcn_s_waitcnt(WAITCNT_VM8);
    } else if (k == KIT - 2) {
      __builtin_amdgcn_s_waitcnt(WAITCNT_VM4);
    } else {
      __builtin_amdgcn_s_waitcnt(WAITCNT_VM0);
    }
    __builtin_amdgcn_sched_barrier(0);
    __builtin_amdgcn_s_barrier();
    COMPUTE(cur);
    if (k < KIT - 1) {
      __builtin_amdgcn_s_barrier();
      __builtin_amdgcn_sched_barrier(0);
    }
  }

#undef ISSUE
#undef COMPUTE

  // Epilogue: partial = acc/256 (bf16), COL-MAJOR per tile (col*128 + row).
  // 32x32 C/D layout: col = lane&31, row = (reg&3) + 8*(reg>>2) + 4*(lane>>5).
  unsigned short* dst = P + (size_t)(t * KSPLIT + kz) * 16384;
  const int cc = lane & 31;
  const int cr = (lane >> 5) * 4;
#pragma unroll
  for (int mi = 0; mi < 2; mi++) {
#pragma unroll
    for (int ni = 0; ni < 2; ni++) {
      const int col = wc * 64 + ni * 32 + cc;
#pragma unroll
      for (int q = 0; q < 4; q++) {
        const int row = wr * 64 + mi * 32 + q * 8 + cr;
        unsigned int d0 = (unsigned int)f32_to_bf16(acc[mi][ni][q * 4 + 0] * PART_SCALE) |
                          ((unsigned int)f32_to_bf16(acc[mi][ni][q * 4 + 1] * PART_SCALE) << 16);
        unsigned int d1 = (unsigned int)f32_to_bf16(acc[mi][ni][q * 4 + 2] * PART_SCALE) |
                          ((unsigned int)f32_to_bf16(acc[mi][ni][q * 4 + 3] * PART_SCALE) << 16);
        uint2 v; v.x = d0; v.y = d1;
        *(uint2*)(dst + (size_t)col * 128 + row) = v;
      }
    }
  }
}

// ------- Kernel 3A: quartered combine -> T/WS/NUM. Grid (136, 4), 256 threads. -------
// R8's verified per-element logic, partitioned into 4 col-quarter blocks per tile so
// 544 blocks cover all CUs (R8's 136-block monolith was 48us of exposed latency).
// Quarter h handles tile cols [h*32, h*32+32); WS/T are atomic so quarter sums add up.
__global__ __launch_bounds__(256) void k_combine_q(const unsigned short* __restrict__ P,
                                                   float* __restrict__ T,
                                                   float* __restrict__ WS,
                                                   float* __restrict__ NUM) {
  __shared__ float tileE[32 * 132];   // col-major: tileE[cl*132 + row]
  const int t = blockIdx.x;
  const int h = blockIdx.y;           // col quarter
  int ti = 0, rem = t;
  while (rem >= 16 - ti) { rem -= 16 - ti; ti++; }
  const int tj = ti + rem;
  const int gr = ti * 128, gc = tj * 128;
  const int c0 = h * 32;
  const int tid = threadIdx.x;
  const int cl = tid >> 3;            // local col 0..31
  const int q  = tid & 7;             // row chunk (16 rows)

  // Phase 1: sum partials, exp, NUM extraction, col partial sums (R1 mapping).
  float cs = 0.f;
  {
    const ushortx8* p0 = (const ushortx8*)(P + (size_t)(t * KSPLIT + 0) * 16384 +
                                           (size_t)(c0 + cl) * 128 + q * 16);
    const ushortx8* p1 = (const ushortx8*)(P + (size_t)(t * KSPLIT + 1) * 16384 +
                                           (size_t)(c0 + cl) * 128 + q * 16);
    const int colg = gc + c0 + cl;
#pragma unroll
    for (int c2 = 0; c2 < 2; c2++) {
      ushortx8 u0 = p0[c2];
      ushortx8 u1 = p1[c2];
#pragma unroll
      for (int e = 0; e < 8; e++) {
        const int r = q * 16 + c2 * 8 + e;
        const float v = (bf16_to_f32((unsigned short)u0[e]) +
                         bf16_to_f32((unsigned short)u1[e])) * INV_TEMP;
        const float ev = __expf(v);
        tileE[cl * 132 + r] = ev;
        cs += ev;
        const int D = (colg - gr - r) & (NROWS - 1);
        if (D == 4 || D == 12) num_store(NUM, gr + r, D, v);
        if (ti != tj && (D == 2044 || D == 2036)) num_store(NUM, colg, 2048 - D, v);
      }
    }
  }
  cs += __shfl_xor(cs, 1, 64);
  cs += __shfl_xor(cs, 2, 64);
  cs += __shfl_xor(cs, 4, 64);
  if (q == 0) atomicAdd(&T[gc + c0 + cl], cs);
  __syncthreads();

  // Phase 2: row sums (off-diagonal): r = tid>>1, halves hh sum 16 cols each.
  if (ti != tj) {
    const int r = tid >> 1;
    const int hh = tid & 1;
    float rs = 0.f;
#pragma unroll
    for (int e = 0; e < 16; e++) rs += tileE[(hh * 16 + e) * 132 + r];
    rs += __shfl_xor(rs, 1, 64);
    if (hh == 0) atomicAdd(&T[gr + r], rs);
  }

  // Phase 3a: main-orientation window sums: row R = gr+tid over this quarter's cols.
  if (tid < 128) {
    const int R = gr + tid;
#pragma unroll
    for (int k = 0; k < 6; k++) {
      const int aa = (R - 4 * k) & (NROWS - 1);
      if (aa % 12 < 4) {
        const int p2 = (aa / 12) * 4 + (aa % 12);
        const int csel = aa & 3;
        const int j0 = (((gc + c0) >> 2) - (aa >> 2)) & 511;
        float w = 0.f;
#pragma unroll
        for (int i2 = 0; i2 < 8; i2++) {
          const int j = j0 + i2;
          if (j < 160 || j >= 512) w += tileE[(4 * i2 + csel) * 132 + tid];
        }
        atomicAdd(&WS[p2 * 6 + k], w);
      }
    }
  } else if (tid < 160 && ti != tj) {
    // Phase 3b: mirror-orientation window sums: row R = gc+c0+cl over cols [gr, gr+128).
    const int cl2 = tid - 128;
    const int R = gc + c0 + cl2;
#pragma unroll
    for (int k = 0; k < 6; k++) {
      const int aa = (R - 4 * k) & (NROWS - 1);
      if (aa % 12 < 4) {
        const int p2 = (aa / 12) * 4 + (aa % 12);
        const int csel = aa & 3;
        const int j0 = ((gr >> 2) - (aa >> 2)) & 511;
        float w = 0.f;
#pragma unroll
        for (int i2 = 0; i2 < 32; i2++) {
          const int j = j0 + i2;
          if (j < 160 || j >= 512) w += tileE[cl2 * 132 + 4 * i2 + csel];
        }
        atomicAdd(&WS[p2 * 6 + k], w);
      }
    }
  }
}

// ---- Kernel 4A: finisher. 19 blocks; Ds = T - WS; loss terms from NUM. ----
__global__ __launch_bounds__(256) void k_finalA(const float* __restrict__ NUM,
                                                const float* __restrict__ WS,
                                                const float* __restrict__ T,
                                                float* __restrict__ out) {
  const int pa[7] = {0, 1, 0, 3, 4, 1, 2};
  const int pb[7] = {1, 2, 3, 4, 5, 4, 5};
  const int idx = blockIdx.x * 256 + threadIdx.x;
  float s = 0.f;
  if (idx < NACT * 7) {
    const int p = idx / 7;
    const int q = idx - p * 7;
    const int a0 = 12 * (p >> 2) + (p & 3);
    const int ra = (a0 + 4 * pa[q]) & (NROWS - 1);
    const int rb = (a0 + 4 * pb[q]) & (NROWS - 1);
    const float dsA = T[ra] - WS[p * 6 + pa[q]];
    const float dsB = T[rb] - WS[p * 6 + pb[q]];
    const float num = NUM[idx];
    const float en = __expf(num);
    s = __logf(en + dsA) + __logf(en + dsB) - 2.f * num;
  }
#pragma unroll
  for (int off = 32; off > 0; off >>= 1) s += __shfl_down(s, off, 64);
  if ((threadIdx.x & 63) == 0) atomicAdd(out, s * (1.0f / (6.0f * 512.0f)));
}

// ------------- Path B kernels (fallback when ws is small; fp32 S) -------------
__global__ __launch_bounds__(256) void k_normconv(const float* __restrict__ X,
                                                  unsigned short* __restrict__ Y) {
  const int row = blockIdx.x;
  const float4* xr = (const float4*)(X + (size_t)row * DIM);
  float4 v[4];
  float s = 0.f;
#pragma unroll
  for (int t = 0; t < 4; t++) {
    float4 w = xr[threadIdx.x + t * 256];
    v[t] = w;
    s += w.x * w.x + w.y * w.y + w.z * w.z + w.w * w.w;
  }
#pragma unroll
  for (int off = 32; off > 0; off >>= 1) s += __shfl_down(s, off, 64);
  __shared__ float wsum[4];
  if ((threadIdx.x & 63) == 0) wsum[threadIdx.x >> 6] = s;
  __syncthreads();
  const float total = wsum[0] + wsum[1] + wsum[2] + wsum[3];
  const float inv = 1.0f / fmaxf(sqrtf(total), 1e-30f);
  ushort4* yr = (ushort4*)(Y + (size_t)row * DIM);
#pragma unroll
  for (int t = 0; t < 4; t++) {
    float4 w = v[t];
    ushort4 o;
    o.x = f32_to_bf16(w.x * inv);
    o.y = f32_to_bf16(w.y * inv);
    o.z = f32_to_bf16(w.z * inv);
    o.w = f32_to_bf16(w.w * inv);
    yr[threadIdx.x + t * 256] = o;
  }
}

__global__ __launch_bounds__(256) void k_gemm(const unsigned short* __restrict__ Y,
                                              float* __restrict__ S) {
  __shared__ __attribute__((aligned(16))) unsigned short sA[128 * 32];
  __shared__ __attribute__((aligned(16))) unsigned short sB[128 * 32];
  const int tid  = threadIdx.x;
  const int lane = tid & 63;
  const int wave = tid >> 6;
  const int wr = wave >> 1;
  const int wc = wave & 1;
  const int row0 = blockIdx.y * 128;
  const int col0 = blockIdx.x * 128;

  floatx4 zero = {0.f, 0.f, 0.f, 0.f};
  floatx4 acc[4][4];
#pragma unroll
  for (int i = 0; i < 4; i++)
#pragma unroll
    for (int j = 0; j < 4; j++) acc[i][j] = zero;

  const int sr = tid >> 2;
  const int sc = (tid & 3) * 8;
  const unsigned short* gA0 = Y + (size_t)(row0 + sr) * DIM + sc;
  const unsigned short* gA1 = gA0 + (size_t)64 * DIM;
  const unsigned short* gB0 = Y + (size_t)(col0 + sr) * DIM + sc;
  const unsigned short* gB1 = gB0 + (size_t)64 * DIM;

  const int fr = lane & 15;
  const int fc = (lane >> 4) * 8;

  for (int k0 = 0; k0 < DIM; k0 += 32) {
    __builtin_amdgcn_global_load_lds(
        (const __attribute__((address_space(1))) void*)(gA0 + k0),
        (__attribute__((address_space(3))) void*)(sA + tid * 8), 16, 0, 0);
    __builtin_amdgcn_global_load_lds(
        (const __attribute__((address_space(1))) void*)(gA1 + k0),
        (__attribute__((address_space(3))) void*)(sA + 2048 + tid * 8), 16, 0, 0);
    __builtin_amdgcn_global_load_lds(
        (const __attribute__((address_space(1))) void*)(gB0 + k0),
        (__attribute__((address_space(3))) void*)(sB + tid * 8), 16, 0, 0);
    __builtin_amdgcn_global_load_lds(
        (const __attribute__((address_space(1))) void*)(gB1 + k0),
        (__attribute__((address_space(3))) void*)(sB + 2048 + tid * 8), 16, 0, 0);
    __syncthreads();

    shortx8 af[4], bf[4];
#pragma unroll
    for (int mi = 0; mi < 4; mi++)
      af[mi] = *(const shortx8*)(sA + (wr * 64 + mi * 16 + fr) * 32 + fc);
#pragma unroll
    for (int ni = 0; ni < 4; ni++)
      bf[ni] = *(const shortx8*)(sB + (wc * 64 + ni * 16 + fr) * 32 + fc);
#pragma unroll
    for (int mi = 0; mi < 4; mi++)
#pragma unroll
      for (int ni = 0; ni < 4; ni++)
        acc[mi][ni] = __builtin_amdgcn_mfma_f32_16x16x32_bf16(af[mi], bf[ni], acc[mi][ni], 0, 0, 0);
    __syncthreads();
  }

  const int cc  = lane & 15;
  const int cr4 = (lane >> 4) * 4;
#pragma unroll
  for (int mi = 0; mi < 4; mi++) {
    const int row = row0 + wr * 64 + mi * 16 + cr4;
#pragma unroll
    for (int ni = 0; ni < 4; ni++) {
      const int col = col0 + wc * 64 + ni * 16 + cc;
      float* dst = S + (size_t)row * NROWS + col;
#pragma unroll
      for (int r = 0; r < 4; r++) dst[(size_t)r * NROWS] = acc[mi][ni][r] * INV_TEMP;
    }
  }
}

__global__ __launch_bounds__(256) void k_rowsum(const float* __restrict__ S,
                                                float* __restrict__ T) {
  const int row = blockIdx.x;
  const float* sr = S + (size_t)row * NROWS;
  float s = 0.f;
  for (int b = threadIdx.x; b < NROWS; b += 256) s += __expf(sr[b]);
#pragma unroll
  for (int off = 32; off > 0; off >>= 1) s += __shfl_down(s, off, 64);
  __shared__ float wsum[4];
  if ((threadIdx.x & 63) == 0) wsum[threadIdx.x >> 6] = s;
  __syncthreads();
  if (threadIdx.x == 0) T[row] = wsum[0] + wsum[1] + wsum[2] + wsum[3];
}

__global__ __launch_bounds__(64) void k_dsum(const float* __restrict__ S,
                                             const float* __restrict__ T,
                                             float* __restrict__ Ds) {
  const int p = blockIdx.x;
  const int k = blockIdx.y;
  const int a = 12 * (p >> 2) + (p & 3);
  const int lane = threadIdx.x;
  const int row = (a + 4 * k) & (NROWS - 1);
  const int m = a >> 2;
  const int c = a & 3;
  const float4* sr4 = (const float4*)(S + (size_t)row * NROWS);
  float s = 0.f;
  {
    float4 v0 = sr4[(m + lane) & 511];
    float4 v1 = sr4[(m + 64 + lane) & 511];
    float e0 = c == 0 ? v0.x : c == 1 ? v0.y : c == 2 ? v0.z : v0.w;
    float e1 = c == 0 ? v1.x : c == 1 ? v1.y : c == 2 ? v1.z : v1.w;
    s += __expf(e0) + __expf(e1);
    if (lane < 32) {
      float4 v2 = sr4[(m + 128 + lane) & 511];
      float e2 = c == 0 ? v2.x : c == 1 ? v2.y : c == 2 ? v2.z : v2.w;
      s += __expf(e2);
    }
  }
#pragma unroll
  for (int off = 32; off > 0; off >>= 1) s += __shfl_down(s, off, 64);
  if (lane == 0) Ds[p * 6 + k] = T[row] - s;
}

__global__ __launch_bounds__(256) void k_final(const float* __restrict__ S,
                                               const float* __restrict__ Ds,
                                               float* __restrict__ out) {
  const int pa[7] = {0, 1, 0, 3, 4, 1, 2};
  const int pb[7] = {1, 2, 3, 4, 5, 4, 5};
  const int idx = blockIdx.x * 256 + threadIdx.x;
  float s = 0.f;
  if (idx < NACT * 7) {
    const int p = idx / 7;
    const int q = idx - p * 7;
    const int a0 = 12 * (p >> 2) + (p & 3);
    const int ra = (a0 + 4 * pa[q]) & (NROWS - 1);
    const int rb = (a0 + 4 * pb[q]) & (NROWS - 1);
    const float num = S[(size_t)ra * NROWS + rb];
    const float en = __expf(num);
    s = __logf(en + Ds[p * 6 + pa[q]]) + __logf(en + Ds[p * 6 + pb[q]]) - 2.f * num;
  }
#pragma unroll
  for (int off = 32; off > 0; off >>= 1) s += __shfl_down(s, off, 64);
  if ((threadIdx.x & 63) == 0) atomicAdd(out, s * (1.0f / (6.0f * 512.0f)));
}

extern "C" void kernel_launch(void* const* d_in, const int* in_sizes, int n_in,
                              void* d_out, int out_size, void* d_ws, size_t ws_size,
                              hipStream_t stream) {
  const float* X = (const float*)d_in[0];
  char* ws = (char*)d_ws;
  float* out = (float*)d_out;

  const size_t pOff = (size_t)32 * 1024 * 1024;
  const size_t needA = pOff + 8192 + 24576 + 24576;   // T + WS + NUM

  if (ws_size >= needA) {
    unsigned char* Yq = (unsigned char*)ws;                                 // 8 MB fp8
    unsigned short* P = (unsigned short*)(ws + (size_t)16 * 1024 * 1024);   // 8.9 MB
    float* T   = (float*)(ws + pOff);                  // 2048 f32
    float* WS  = (float*)(ws + pOff + 8192);           // 4104 f32 window sums
    float* NUM = (float*)(ws + pOff + 8192 + 24576);   // 4788 f32 pair numerators
    hipLaunchKernelGGL(k_normconv_fp8, dim3(NROWS), dim3(256), 0, stream, X, Yq, T, WS, out);
    hipLaunchKernelGGL(k_gemm_mx, dim3(NTILE128 * KSPLIT), dim3(256), 0, stream, Yq, P);
    hipLaunchKernelGGL(k_combine_q, dim3(NTILE128, 4), dim3(256), 0, stream, P, T, WS, NUM);
    hipLaunchKernelGGL(k_finalA, dim3((NACT * 7 + 255) / 256), dim3(256), 0, stream,
                       NUM, WS, T, out);
  } else {
    unsigned short* Y = (unsigned short*)ws;                      // 16 MB bf16
    float* S = (float*)(ws + (size_t)16 * 1024 * 1024);           // 16 MB fp32
    float* T  = (float*)(ws + pOff);
    float* Ds = (float*)(ws + pOff + 8192);
    hipMemsetAsync(out, 0, sizeof(float), stream);
    hipLaunchKernelGGL(k_normconv, dim3(NROWS), dim3(256), 0, stream, X, Y);
    hipLaunchKernelGGL(k_gemm, dim3(16, 16), dim3(256), 0, stream, Y, S);
    hipLaunchKernelGGL(k_rowsum, dim3(NROWS), dim3(256), 0, stream, S, T);
    hipLaunchKernelGGL(k_dsum, dim3(NACT, 6), dim3(64), 0, stream, S, T, Ds);
    hipLaunchKernelGGL(k_final, dim3((NACT * 7 + 255) / 256), dim3(256), 0, stream, S, Ds, out);
  }
}